// Round 5
// baseline (749.024 us; speedup 1.0000x reference)
//
#include <hip/hip_runtime.h>
#include <math.h>

// ---------------------------------------------------------------------------
// SAGE pipeline, bf16-MFMA, XCD-sliced gather edition.
//   M = 2N rows (0..N-1 clean, N..2N-1 noisy) batched through each GEMM.
//   GEMM epilogues write BRANCH-INTERLEAVED layouts:
//     P2[node][2][128] bf16 (512 B rows), R2[node][2][128] f32   (layers 0/1)
//     Pz[node][2][64] bf16 (256 B rows), Rz[node][2][64] f32     (layer 2)
//   Aggregation slices each row into 64 B column-slices and pins slice s to
//   blocks with blockIdx%NS==s (round-robin XCD dispatch): each XCD then
//   gathers from a 3.2 MB sub-table that fits its private 4 MB L2.
//   Round-4 evidence: un-sliced gather re-fetched the 25.6 MB table as
//   204 MB of L2-miss traffic (~8x) at 4.15 TB/s.
// ---------------------------------------------------------------------------

typedef unsigned int uint;
typedef unsigned short ushort;
typedef short bf16x8 __attribute__((ext_vector_type(8)));
typedef float f32x4 __attribute__((ext_vector_type(4)));

__device__ __forceinline__ ushort f2b(float f) {  // fp32 -> bf16 RNE
  union { float f; uint u; } v; v.f = f;
  uint u = v.u;
  return (ushort)((u + 0x7FFFu + ((u >> 16) & 1u)) >> 16);
}
__device__ __forceinline__ float b2f_lo(uint u) {
  union { uint u; float f; } v; v.u = u << 16; return v.f;
}
__device__ __forceinline__ float b2f_hi(uint u) {
  union { uint u; float f; } v; v.u = u & 0xFFFF0000u; return v.f;
}

// ------------------------------- CSR build --------------------------------
__global__ __launch_bounds__(256) void count_kernel(
    const int* __restrict__ dst, int* __restrict__ cnt, int E) {
  int e = blockIdx.x * blockDim.x + threadIdx.x;
  if (e >= E) return;
  atomicAdd(&cnt[dst[e]], 1);
}

// pass 1: per-block (1024 elems) local exclusive scan + block total.
__global__ __launch_bounds__(256) void scan_blocks(
    const int* __restrict__ cnt, int* __restrict__ loc,
    int* __restrict__ bsum, int n) {
  __shared__ int ls[4];
  int t = threadIdx.x;
  int base = blockIdx.x * 1024 + t * 4;
  int v[4];
  int s = 0;
#pragma unroll
  for (int i = 0; i < 4; ++i) {
    v[i] = (base + i < n) ? cnt[base + i] : 0;
    s += v[i];
  }
  int lane = t & 63, wid = t >> 6;
  int ps = s;
#pragma unroll
  for (int d = 1; d < 64; d <<= 1) {
    int o = __shfl_up(ps, d, 64);
    if (lane >= d) ps += o;
  }
  if (lane == 63) ls[wid] = ps;
  __syncthreads();
  if (t == 0) {
    int r = 0;
#pragma unroll
    for (int w = 0; w < 4; ++w) { int x = ls[w]; ls[w] = r; r += x; }
  }
  __syncthreads();
  int run = ps - s + ls[wid];
#pragma unroll
  for (int i = 0; i < 4; ++i) {
    if (base + i < n) loc[base + i] = run;
    run += v[i];
  }
  if (t == 255) bsum[blockIdx.x] = ps + ls[wid];
}

// pass 2: exclusive scan of block sums (nb <= 256), single block.
__global__ __launch_bounds__(256) void scan_bsums(int* __restrict__ bsum,
                                                  int nb) {
  __shared__ int ls[4];
  int t = threadIdx.x;
  int v = (t < nb) ? bsum[t] : 0;
  int lane = t & 63, wid = t >> 6;
  int ps = v;
#pragma unroll
  for (int d = 1; d < 64; d <<= 1) {
    int o = __shfl_up(ps, d, 64);
    if (lane >= d) ps += o;
  }
  if (lane == 63) ls[wid] = ps;
  __syncthreads();
  if (t == 0) {
    int r = 0;
#pragma unroll
    for (int w = 0; w < 4; ++w) { int x = ls[w]; ls[w] = r; r += x; }
  }
  __syncthreads();
  if (t < nb) bsum[t] = ps - v + ls[wid];
}

// pass 3: add block offsets; write off, cur, off[n]=E.
__global__ __launch_bounds__(256) void scan_apply(
    const int* __restrict__ loc, const int* __restrict__ bsum,
    int* __restrict__ off, int* __restrict__ cur, int n, int E) {
  int i = blockIdx.x * 256 + threadIdx.x;
  if (i < n) {
    int v = loc[i] + bsum[i >> 10];
    off[i] = v;
    cur[i] = v;
  }
  if (i == 0) off[n] = E;
}

__global__ __launch_bounds__(256) void fill_kernel(
    const int* __restrict__ src, const int* __restrict__ dst,
    int* __restrict__ cur, int* __restrict__ csr, int E) {
  int e = blockIdx.x * blockDim.x + threadIdx.x;
  if (e >= E) return;
  int pos = atomicAdd(&cur[dst[e]], 1);
  csr[pos] = src[e];
}

// --------------------- input prep: noisy + bf16 convert --------------------
__global__ __launch_bounds__(256) void noisy_convert(
    const float* __restrict__ x, const float* __restrict__ noise,
    ushort* __restrict__ XB, int N) {
  int node = (blockIdx.x * blockDim.x + threadIdx.x) >> 6;
  int lane = threadIdx.x & 63;
  if (node >= N) return;
  size_t base = (size_t)node * 128 + 2 * lane;
  float2 nz = *(const float2*)(noise + base);
  float ss = nz.x * nz.x + nz.y * nz.y;
#pragma unroll
  for (int m = 1; m < 64; m <<= 1) ss += __shfl_xor(ss, m, 64);
  float scale = 0.1f / fmaxf(sqrtf(ss), 1e-12f);
  float2 xv = *(const float2*)(x + base);
  float s0 = (xv.x > 0.f) ? 1.f : ((xv.x < 0.f) ? -1.f : 0.f);
  float s1 = (xv.y > 0.f) ? 1.f : ((xv.y < 0.f) ? -1.f : 0.f);
  float n0 = xv.x + s0 * nz.x * scale;
  float n1 = xv.y + s1 * nz.y * scale;
  uint pc = ((uint)f2b(xv.y) << 16) | f2b(xv.x);
  uint pn = ((uint)f2b(n1) << 16) | f2b(n0);
  *(uint*)(XB + base) = pc;
  *(uint*)(XB + (size_t)N * 128 + base) = pn;
}

__global__ __launch_bounds__(256) void conv_weights(
    const float* __restrict__ Wl0, const float* __restrict__ Wr0,
    const float* __restrict__ Wl1, const float* __restrict__ Wr1,
    const float* __restrict__ Wl2, const float* __restrict__ Wr2,
    ushort* __restrict__ WB0, ushort* __restrict__ WB1,
    ushort* __restrict__ WB2) {
  int i = blockIdx.x * 256 + threadIdx.x;
  if (i < 16384) {
    WB0[i] = f2b(Wl0[i]);
    WB0[16384 + i] = f2b(Wr0[i]);
    WB1[i] = f2b(Wl1[i]);
    WB1[16384 + i] = f2b(Wr1[i]);
  }
  if (i < 6016) {
    WB2[i] = f2b(Wl2[i]);
    WB2[6016 + i] = f2b(Wr2[i]);
  }
}

// ------------------------------- GEMM (bf16) -------------------------------
// A:[M][128] bf16 (row = branch*N+node). W rows = output cols.
// !L2 grid (rb,2): y=0 -> Wl -> P2[node][2][128] bf16
//                  y=1 -> Wr -> R2[node][2][128] f32
// L2  grid (rb,1): 94 W rows; col<47 -> Pz[node][2][64] bf16 (pad unwritten)
//                  col in [47,94) -> Rz[node][2][64] f32
template <int NT, bool L2>
__global__ __launch_bounds__(256) void gemm_bf16(
    const ushort* __restrict__ A, const ushort* __restrict__ W,
    ushort* __restrict__ Pb, float* __restrict__ Rf, int M) {
  constexpr int BN = NT * 32;
  constexpr int WROWS = L2 ? 94 : 128;
  __shared__ ushort As[128 * 72];   // row stride 72 bf16 = 144 B (bank-safe)
  __shared__ ushort Ws[BN * 72];
  int tid = threadIdx.x;
  int lane = tid & 63, wid = tid >> 6;
  int wm = wid & 1, wn = wid >> 1;
  int lrow = lane & 15, quad = lane >> 4;
  int row0 = blockIdx.x * 128;
  int N0 = M >> 1;
  const ushort* Wb = W + (size_t)blockIdx.y * (128 * 128);

  f32x4 acc[4][NT];
#pragma unroll
  for (int mt = 0; mt < 4; ++mt)
#pragma unroll
    for (int nt = 0; nt < NT; ++nt) acc[mt][nt] = (f32x4)(0.f);

  for (int k0 = 0; k0 < 128; k0 += 64) {
    for (int c = tid; c < 128 * 8; c += 256) {
      int r = c >> 3, kc = c & 7;
      int gr = row0 + r;
      uint4 v = make_uint4(0, 0, 0, 0);
      if (gr < M) v = *(const uint4*)(A + (size_t)gr * 128 + k0 + kc * 8);
      *(uint4*)(As + r * 72 + kc * 8) = v;
    }
    for (int c = tid; c < BN * 8; c += 256) {
      int r = c >> 3, kc = c & 7;
      uint4 v = make_uint4(0, 0, 0, 0);
      if (r < WROWS) v = *(const uint4*)(Wb + (size_t)r * 128 + k0 + kc * 8);
      *(uint4*)(Ws + r * 72 + kc * 8) = v;
    }
    __syncthreads();
#pragma unroll
    for (int ks = 0; ks < 64; ks += 32) {
      bf16x8 af[4], bw[NT];
#pragma unroll
      for (int mt = 0; mt < 4; ++mt)
        af[mt] = *(const bf16x8*)(As + (wm * 64 + mt * 16 + lrow) * 72 + ks + quad * 8);
#pragma unroll
      for (int nt = 0; nt < NT; ++nt)
        bw[nt] = *(const bf16x8*)(Ws + (wn * NT * 16 + nt * 16 + lrow) * 72 + ks + quad * 8);
#pragma unroll
      for (int mt = 0; mt < 4; ++mt)
#pragma unroll
        for (int nt = 0; nt < NT; ++nt)
          acc[mt][nt] = __builtin_amdgcn_mfma_f32_16x16x32_bf16(
              af[mt], bw[nt], acc[mt][nt], 0, 0, 0);
    }
    __syncthreads();
  }
  // epilogue: C/D layout col=lane&15, row=quad*4+reg; branch-interleaved out
#pragma unroll
  for (int mt = 0; mt < 4; ++mt) {
#pragma unroll
    for (int nt = 0; nt < NT; ++nt) {
#pragma unroll
      for (int rg = 0; rg < 4; ++rg) {
        int row = row0 + wm * 64 + mt * 16 + quad * 4 + rg;
        if (row >= M) continue;
        int col = wn * NT * 16 + nt * 16 + lrow;
        int nd = (row < N0) ? row : row - N0;
        int hf = (row < N0) ? 0 : 1;
        float v = acc[mt][nt][rg];
        if (!L2) {
          size_t idx = (size_t)nd * 256 + hf * 128 + col;
          if (blockIdx.y == 0)
            Pb[idx] = f2b(v);
          else
            Rf[idx] = v;
        } else {
          if (col < 47)
            Pb[(size_t)nd * 128 + hf * 64 + col] = f2b(v);
          else if (col < 94)
            Rf[(size_t)nd * 128 + hf * 64 + (col - 47)] = v;
        }
      }
    }
  }
}

// ----------------------- sliced aggregation (layers 0/1) -------------------
// Block handles slice = blockIdx%8 (64 B of each 512 B P2 row) for 4 nodes.
// Round-robin block->XCD dispatch pins each 3.2 MB slice to one XCD's L2.
// Wave: 4 edges x 16 lanes; lane li sums dual-cols {slice*32+2li, +1}.
template <bool WF32>
__global__ __launch_bounds__(256) void agg_slice128(
    const ushort* __restrict__ P2, const float* __restrict__ R2,
    const float* __restrict__ bias, const int* __restrict__ off,
    const int* __restrict__ csr, float* __restrict__ f0,
    float* __restrict__ f1, ushort* __restrict__ bout, int N) {
  int slice = blockIdx.x & 7;
  int node = (blockIdx.x >> 3) * 4 + (threadIdx.x >> 6);
  int lane = threadIdx.x & 63;
  if (node >= N) return;
  int eg = lane >> 4, li = lane & 15;
  const ushort* Ps = P2 + slice * 32 + li * 2;
  int b = off[node], e = off[node + 1];
  float a0 = 0.f, a1 = 0.f, c0 = 0.f, c1 = 0.f;
  int j = b;
  for (; j + 8 <= e; j += 8) {
    int s0 = csr[j + eg];
    int s1 = csr[j + 4 + eg];
    uint u0 = *(const uint*)(Ps + (size_t)s0 * 256);
    uint u1 = *(const uint*)(Ps + (size_t)s1 * 256);
    a0 += b2f_lo(u0); a1 += b2f_hi(u0);
    c0 += b2f_lo(u1); c1 += b2f_hi(u1);
  }
  for (; j < e; j += 4) {
    int ej = j + eg;
    uint u = 0;
    if (ej < e) u = *(const uint*)(Ps + (size_t)csr[ej] * 256);
    a0 += b2f_lo(u); a1 += b2f_hi(u);
  }
  a0 += c0; a1 += c1;
  a0 += __shfl_xor(a0, 16, 64); a1 += __shfl_xor(a1, 16, 64);
  a0 += __shfl_xor(a0, 32, 64); a1 += __shfl_xor(a1, 32, 64);
  if (lane >= 16) return;
  float invd = 1.f / (float)max(e - b, 1);
  int d = slice * 32 + li * 2;   // dual col 0..255
  int cb = d & 127;              // col within branch
  int br = d >> 7;
  float2 rv = *(const float2*)(R2 + (size_t)node * 256 + d);
  float o0 = fmaxf(a0 * invd + bias[cb] + rv.x, 0.f);
  float o1 = fmaxf(a1 * invd + bias[cb + 1] + rv.y, 0.f);
  uint pk = ((uint)f2b(o1) << 16) | f2b(o0);
  *(uint*)(bout + (size_t)(br ? N + node : node) * 128 + cb) = pk;
  if (WF32) {
    float* dst = (br ? f1 : f0) + (size_t)node * 128 + cb;
    *(float2*)dst = make_float2(o0, o1);
  }
}

// ------------------------ sliced aggregation (layer 2) ---------------------
// Pz rows 256 B -> 4 slices of 64 B; writes z_tmp[node][2][64] f32.
__global__ __launch_bounds__(256) void agg_slice47(
    const ushort* __restrict__ Pz, const float* __restrict__ Rz,
    const float* __restrict__ bias, const int* __restrict__ off,
    const int* __restrict__ csr, float* __restrict__ zt, int N) {
  int slice = blockIdx.x & 3;
  int node = (blockIdx.x >> 2) * 4 + (threadIdx.x >> 6);
  int lane = threadIdx.x & 63;
  if (node >= N) return;
  int eg = lane >> 4, li = lane & 15;
  const ushort* Ps = Pz + slice * 32 + li * 2;
  int b = off[node], e = off[node + 1];
  float a0 = 0.f, a1 = 0.f, c0 = 0.f, c1 = 0.f;
  int j = b;
  for (; j + 8 <= e; j += 8) {
    int s0 = csr[j + eg];
    int s1 = csr[j + 4 + eg];
    uint u0 = *(const uint*)(Ps + (size_t)s0 * 128);
    uint u1 = *(const uint*)(Ps + (size_t)s1 * 128);
    a0 += b2f_lo(u0); a1 += b2f_hi(u0);
    c0 += b2f_lo(u1); c1 += b2f_hi(u1);
  }
  for (; j < e; j += 4) {
    int ej = j + eg;
    uint u = 0;
    if (ej < e) u = *(const uint*)(Ps + (size_t)csr[ej] * 128);
    a0 += b2f_lo(u); a1 += b2f_hi(u);
  }
  a0 += c0; a1 += c1;
  a0 += __shfl_xor(a0, 16, 64); a1 += __shfl_xor(a1, 16, 64);
  a0 += __shfl_xor(a0, 32, 64); a1 += __shfl_xor(a1, 32, 64);
  if (lane >= 16) return;
  float invd = 1.f / (float)max(e - b, 1);
  int d = slice * 32 + li * 2;   // 0..127 within [2][64]
  int c = d & 63;                // col within branch (pad64)
  float2 rv = *(const float2*)(Rz + (size_t)node * 128 + d);
  float z0 = a0 * invd + (c < 47 ? bias[c] : 0.f) + rv.x;
  float z1 = a1 * invd + (c + 1 < 47 ? bias[c + 1] : 0.f) + rv.y;
  *(float2*)(zt + (size_t)node * 128 + d) = make_float2(z0, z1);
}

// z_tmp [node][2][64] -> z (47-packed) + log_softmax y. 1 wave/node.
__global__ __launch_bounds__(256) void softmax47(
    const float* __restrict__ zt, float* __restrict__ z0f,
    float* __restrict__ z1f, float* __restrict__ y0f,
    float* __restrict__ y1f, int N) {
  int node = (blockIdx.x * blockDim.x + threadIdx.x) >> 6;
  int lane = threadIdx.x & 63;
  if (node >= N) return;
  int half = lane >> 5, lq = lane & 31;
  int c0 = 2 * lq, c1 = c0 + 1;
  bool v0 = c0 < 47, v1 = c1 < 47;
  float2 zv = *(const float2*)(zt + (size_t)node * 128 + half * 64 + c0);
  float za = v0 ? zv.x : -INFINITY;
  float zb = v1 ? zv.y : -INFINITY;
  float m = fmaxf(za, zb);
#pragma unroll
  for (int d = 1; d < 32; d <<= 1) m = fmaxf(m, __shfl_xor(m, d, 64));
  float s = (v0 ? __expf(za - m) : 0.f) + (v1 ? __expf(zb - m) : 0.f);
#pragma unroll
  for (int d = 1; d < 32; d <<= 1) s += __shfl_xor(s, d, 64);
  float ls = logf(s) + m;
  float* zo = (half ? z1f : z0f) + (size_t)node * 47;
  float* yo = (half ? y1f : y0f) + (size_t)node * 47;
  if (v0) { zo[c0] = zv.x; yo[c0] = zv.x - ls; }
  if (v1) { zo[c1] = zv.y; yo[c1] = zv.y - ls; }
}

// ---------------------------------------------------------------------------
extern "C" void kernel_launch(void* const* d_in, const int* in_sizes, int n_in,
                              void* d_out, int out_size, void* d_ws,
                              size_t ws_size, hipStream_t stream) {
  const float* x = (const float*)d_in[0];
  const int* ei = (const int*)d_in[1];
  const float* noise = (const float*)d_in[2];
  const float* Wl0 = (const float*)d_in[3];
  const float* bl0 = (const float*)d_in[4];
  const float* Wr0 = (const float*)d_in[5];
  const float* Wl1 = (const float*)d_in[6];
  const float* bl1 = (const float*)d_in[7];
  const float* Wr1 = (const float*)d_in[8];
  const float* Wl2 = (const float*)d_in[9];
  const float* bl2 = (const float*)d_in[10];
  const float* Wr2 = (const float*)d_in[11];

  const int N = in_sizes[0] / 128;
  const int E = in_sizes[1] / 2;
  const int M = 2 * N;

  float* out = (float*)d_out;
  float* h_p = out;
  float* y_p = h_p + (size_t)N * 128;
  float* z_p = y_p + (size_t)N * 47;
  float* h_n = z_p + (size_t)N * 47;
  float* y_n = h_n + (size_t)N * 128;
  float* z_n = y_n + (size_t)N * 47;

  char* w = (char*)d_ws;
  auto alloc = [&](size_t bytes) {
    void* p = (void*)w;
    w += (bytes + 511) & ~(size_t)511;
    return p;
  };
  ushort* XB = (ushort*)alloc((size_t)M * 128 * 2);   // activations bf16 [M][128]
  ushort* Pb = (ushort*)alloc((size_t)M * 128 * 2);   // P2 / Pz interleaved
  float* Rf = (float*)alloc((size_t)M * 128 * 4);     // R2; as Rz uses lower half
  ushort* WB0 = (ushort*)alloc(256 * 128 * 2);
  ushort* WB1 = (ushort*)alloc(256 * 128 * 2);
  ushort* WB2 = (ushort*)alloc(94 * 128 * 2);
  int* cnt = (int*)alloc((size_t)N * 4);
  int* off = (int*)alloc((size_t)(N + 1) * 4);
  int* cur = (int*)alloc((size_t)N * 4);
  int* loc = (int*)alloc((size_t)N * 4);
  int* bsum = (int*)alloc((size_t)256 * 4);
  int* csr = (int*)alloc((size_t)E * 4);
  float* zt = Rf + (size_t)N * 128;  // layer-2 z_tmp in unused upper half of Rf

  conv_weights<<<(16384 + 255) / 256, 256, 0, stream>>>(
      Wl0, Wr0, Wl1, Wr1, Wl2, Wr2, WB0, WB1, WB2);

  // CSR build
  hipMemsetAsync(cnt, 0, (size_t)N * 4, stream);
  int eb = (E + 255) / 256;
  count_kernel<<<eb, 256, 0, stream>>>(ei + E, cnt, E);
  int sb = (N + 1023) / 1024;
  scan_blocks<<<sb, 256, 0, stream>>>(cnt, loc, bsum, N);
  scan_bsums<<<1, 256, 0, stream>>>(bsum, sb);
  scan_apply<<<(N + 255) / 256, 256, 0, stream>>>(loc, bsum, off, cur, N, E);
  fill_kernel<<<eb, 256, 0, stream>>>(ei, ei + E, cur, csr, E);

  int nwb = (N + 3) / 4;       // 1 wave/node
  int rb = (M + 127) / 128;    // GEMM row blocks
  int sb128 = nwb * 8;         // sliced agg grids
  int sb47 = nwb * 4;

  noisy_convert<<<nwb, 256, 0, stream>>>(x, noise, XB, N);

  // layer 0
  gemm_bf16<4, false><<<dim3(rb, 2), 256, 0, stream>>>(XB, WB0, Pb, Rf, M);
  agg_slice128<false><<<sb128, 256, 0, stream>>>(Pb, Rf, bl0, off, csr,
                                                 nullptr, nullptr, XB, N);
  // layer 1 (h outputs + bf16 for next layer)
  gemm_bf16<4, false><<<dim3(rb, 2), 256, 0, stream>>>(XB, WB1, Pb, Rf, M);
  agg_slice128<true><<<sb128, 256, 0, stream>>>(Pb, Rf, bl1, off, csr, h_p,
                                                h_n, XB, N);
  // layer 2: sliced agg -> z_tmp, then streaming softmax
  gemm_bf16<3, true><<<dim3(rb, 1), 256, 0, stream>>>(XB, WB2, Pb, Rf, M);
  agg_slice47<<<sb47, 256, 0, stream>>>(Pb, Rf, bl2, off, csr, zt, N);
  softmax47<<<nwb, 256, 0, stream>>>(zt, z_p, z_n, y_p, y_n, N);
}

// Round 6
// 492.002 us; speedup vs baseline: 1.5224x; 1.5224x over previous
//
#include <hip/hip_runtime.h>
#include <math.h>

// ---------------------------------------------------------------------------
// SAGE pipeline, bf16-MFMA, dual-branch-interleaved gather edition (round-4
// structure + unroll-8 gather MLP).
//   M = 2N rows (0..N-1 clean, N..2N-1 noisy) batched through each GEMM.
//   GEMM epilogues write BRANCH-INTERLEAVED layouts:
//     P2[node][2][128] bf16 (512 B rows), R2[node][2][128] f32   (layers 0/1)
//     Pz[node][2][64] bf16 (256 B rows), Rz[node][2][64] f32     (layer 2)
//   One wave per NODE aggregates BOTH branches with ONE request per edge.
//   Round-5 post-mortem: 64B XCD-sliced gathers REGRESSED (69->171 us,
//   FETCH 204->242 MB) - %8 block->XCD pinning gives no L2 exclusivity and
//   slicing multiplies csr reads. Keep full-row requests; raise MLP instead.
// ---------------------------------------------------------------------------

typedef unsigned int uint;
typedef unsigned short ushort;
typedef short bf16x8 __attribute__((ext_vector_type(8)));
typedef float f32x4 __attribute__((ext_vector_type(4)));

__device__ __forceinline__ ushort f2b(float f) {  // fp32 -> bf16 RNE
  union { float f; uint u; } v; v.f = f;
  uint u = v.u;
  return (ushort)((u + 0x7FFFu + ((u >> 16) & 1u)) >> 16);
}
__device__ __forceinline__ float b2f_lo(uint u) {
  union { uint u; float f; } v; v.u = u << 16; return v.f;
}
__device__ __forceinline__ float b2f_hi(uint u) {
  union { uint u; float f; } v; v.u = u & 0xFFFF0000u; return v.f;
}

// ------------------------------- CSR build --------------------------------
__global__ __launch_bounds__(256) void count_kernel(
    const int* __restrict__ dst, int* __restrict__ cnt, int E) {
  int e = blockIdx.x * blockDim.x + threadIdx.x;
  if (e >= E) return;
  atomicAdd(&cnt[dst[e]], 1);
}

// pass 1: per-block (1024 elems) local exclusive scan + block total.
__global__ __launch_bounds__(256) void scan_blocks(
    const int* __restrict__ cnt, int* __restrict__ loc,
    int* __restrict__ bsum, int n) {
  __shared__ int ls[4];
  int t = threadIdx.x;
  int base = blockIdx.x * 1024 + t * 4;
  int v[4];
  int s = 0;
#pragma unroll
  for (int i = 0; i < 4; ++i) {
    v[i] = (base + i < n) ? cnt[base + i] : 0;
    s += v[i];
  }
  int lane = t & 63, wid = t >> 6;
  int ps = s;
#pragma unroll
  for (int d = 1; d < 64; d <<= 1) {
    int o = __shfl_up(ps, d, 64);
    if (lane >= d) ps += o;
  }
  if (lane == 63) ls[wid] = ps;
  __syncthreads();
  if (t == 0) {
    int r = 0;
#pragma unroll
    for (int w = 0; w < 4; ++w) { int x = ls[w]; ls[w] = r; r += x; }
  }
  __syncthreads();
  int run = ps - s + ls[wid];
#pragma unroll
  for (int i = 0; i < 4; ++i) {
    if (base + i < n) loc[base + i] = run;
    run += v[i];
  }
  if (t == 255) bsum[blockIdx.x] = ps + ls[wid];
}

// pass 2: exclusive scan of block sums (nb <= 256), single block.
__global__ __launch_bounds__(256) void scan_bsums(int* __restrict__ bsum,
                                                  int nb) {
  __shared__ int ls[4];
  int t = threadIdx.x;
  int v = (t < nb) ? bsum[t] : 0;
  int lane = t & 63, wid = t >> 6;
  int ps = v;
#pragma unroll
  for (int d = 1; d < 64; d <<= 1) {
    int o = __shfl_up(ps, d, 64);
    if (lane >= d) ps += o;
  }
  if (lane == 63) ls[wid] = ps;
  __syncthreads();
  if (t == 0) {
    int r = 0;
#pragma unroll
    for (int w = 0; w < 4; ++w) { int x = ls[w]; ls[w] = r; r += x; }
  }
  __syncthreads();
  if (t < nb) bsum[t] = ps - v + ls[wid];
}

// pass 3: add block offsets; write off, cur, off[n]=E.
__global__ __launch_bounds__(256) void scan_apply(
    const int* __restrict__ loc, const int* __restrict__ bsum,
    int* __restrict__ off, int* __restrict__ cur, int n, int E) {
  int i = blockIdx.x * 256 + threadIdx.x;
  if (i < n) {
    int v = loc[i] + bsum[i >> 10];
    off[i] = v;
    cur[i] = v;
  }
  if (i == 0) off[n] = E;
}

__global__ __launch_bounds__(256) void fill_kernel(
    const int* __restrict__ src, const int* __restrict__ dst,
    int* __restrict__ cur, int* __restrict__ csr, int E) {
  int e = blockIdx.x * blockDim.x + threadIdx.x;
  if (e >= E) return;
  int pos = atomicAdd(&cur[dst[e]], 1);
  csr[pos] = src[e];
}

// --------------------- input prep: noisy + bf16 convert --------------------
__global__ __launch_bounds__(256) void noisy_convert(
    const float* __restrict__ x, const float* __restrict__ noise,
    ushort* __restrict__ XB, int N) {
  int node = (blockIdx.x * blockDim.x + threadIdx.x) >> 6;
  int lane = threadIdx.x & 63;
  if (node >= N) return;
  size_t base = (size_t)node * 128 + 2 * lane;
  float2 nz = *(const float2*)(noise + base);
  float ss = nz.x * nz.x + nz.y * nz.y;
#pragma unroll
  for (int m = 1; m < 64; m <<= 1) ss += __shfl_xor(ss, m, 64);
  float scale = 0.1f / fmaxf(sqrtf(ss), 1e-12f);
  float2 xv = *(const float2*)(x + base);
  float s0 = (xv.x > 0.f) ? 1.f : ((xv.x < 0.f) ? -1.f : 0.f);
  float s1 = (xv.y > 0.f) ? 1.f : ((xv.y < 0.f) ? -1.f : 0.f);
  float n0 = xv.x + s0 * nz.x * scale;
  float n1 = xv.y + s1 * nz.y * scale;
  uint pc = ((uint)f2b(xv.y) << 16) | f2b(xv.x);
  uint pn = ((uint)f2b(n1) << 16) | f2b(n0);
  *(uint*)(XB + base) = pc;
  *(uint*)(XB + (size_t)N * 128 + base) = pn;
}

__global__ __launch_bounds__(256) void conv_weights(
    const float* __restrict__ Wl0, const float* __restrict__ Wr0,
    const float* __restrict__ Wl1, const float* __restrict__ Wr1,
    const float* __restrict__ Wl2, const float* __restrict__ Wr2,
    ushort* __restrict__ WB0, ushort* __restrict__ WB1,
    ushort* __restrict__ WB2) {
  int i = blockIdx.x * 256 + threadIdx.x;
  if (i < 16384) {
    WB0[i] = f2b(Wl0[i]);
    WB0[16384 + i] = f2b(Wr0[i]);
    WB1[i] = f2b(Wl1[i]);
    WB1[16384 + i] = f2b(Wr1[i]);
  }
  if (i < 6016) {
    WB2[i] = f2b(Wl2[i]);
    WB2[6016 + i] = f2b(Wr2[i]);
  }
}

// ------------------------------- GEMM (bf16) -------------------------------
// A:[M][128] bf16 (row = branch*N+node). W rows = output cols.
// !L2 grid (rb,2): y=0 -> Wl -> P2[node][2][128] bf16
//                  y=1 -> Wr -> R2[node][2][128] f32
// L2  grid (rb,1): 94 W rows; col<47 -> Pz[node][2][64] bf16 (pad unwritten)
//                  col in [47,94) -> Rz[node][2][64] f32
template <int NT, bool L2>
__global__ __launch_bounds__(256) void gemm_bf16(
    const ushort* __restrict__ A, const ushort* __restrict__ W,
    ushort* __restrict__ Pb, float* __restrict__ Rf, int M) {
  constexpr int BN = NT * 32;
  constexpr int WROWS = L2 ? 94 : 128;
  __shared__ ushort As[128 * 72];   // row stride 72 bf16 = 144 B (bank-safe)
  __shared__ ushort Ws[BN * 72];
  int tid = threadIdx.x;
  int lane = tid & 63, wid = tid >> 6;
  int wm = wid & 1, wn = wid >> 1;
  int lrow = lane & 15, quad = lane >> 4;
  int row0 = blockIdx.x * 128;
  int N0 = M >> 1;
  const ushort* Wb = W + (size_t)blockIdx.y * (128 * 128);

  f32x4 acc[4][NT];
#pragma unroll
  for (int mt = 0; mt < 4; ++mt)
#pragma unroll
    for (int nt = 0; nt < NT; ++nt) acc[mt][nt] = (f32x4)(0.f);

  for (int k0 = 0; k0 < 128; k0 += 64) {
    for (int c = tid; c < 128 * 8; c += 256) {
      int r = c >> 3, kc = c & 7;
      int gr = row0 + r;
      uint4 v = make_uint4(0, 0, 0, 0);
      if (gr < M) v = *(const uint4*)(A + (size_t)gr * 128 + k0 + kc * 8);
      *(uint4*)(As + r * 72 + kc * 8) = v;
    }
    for (int c = tid; c < BN * 8; c += 256) {
      int r = c >> 3, kc = c & 7;
      uint4 v = make_uint4(0, 0, 0, 0);
      if (r < WROWS) v = *(const uint4*)(Wb + (size_t)r * 128 + k0 + kc * 8);
      *(uint4*)(Ws + r * 72 + kc * 8) = v;
    }
    __syncthreads();
#pragma unroll
    for (int ks = 0; ks < 64; ks += 32) {
      bf16x8 af[4], bw[NT];
#pragma unroll
      for (int mt = 0; mt < 4; ++mt)
        af[mt] = *(const bf16x8*)(As + (wm * 64 + mt * 16 + lrow) * 72 + ks + quad * 8);
#pragma unroll
      for (int nt = 0; nt < NT; ++nt)
        bw[nt] = *(const bf16x8*)(Ws + (wn * NT * 16 + nt * 16 + lrow) * 72 + ks + quad * 8);
#pragma unroll
      for (int mt = 0; mt < 4; ++mt)
#pragma unroll
        for (int nt = 0; nt < NT; ++nt)
          acc[mt][nt] = __builtin_amdgcn_mfma_f32_16x16x32_bf16(
              af[mt], bw[nt], acc[mt][nt], 0, 0, 0);
    }
    __syncthreads();
  }
  // epilogue: C/D layout col=lane&15, row=quad*4+reg; branch-interleaved out
#pragma unroll
  for (int mt = 0; mt < 4; ++mt) {
#pragma unroll
    for (int nt = 0; nt < NT; ++nt) {
#pragma unroll
      for (int rg = 0; rg < 4; ++rg) {
        int row = row0 + wm * 64 + mt * 16 + quad * 4 + rg;
        if (row >= M) continue;
        int col = wn * NT * 16 + nt * 16 + lrow;
        int nd = (row < N0) ? row : row - N0;
        int hf = (row < N0) ? 0 : 1;
        float v = acc[mt][nt][rg];
        if (!L2) {
          size_t idx = (size_t)nd * 256 + hf * 128 + col;
          if (blockIdx.y == 0)
            Pb[idx] = f2b(v);
          else
            Rf[idx] = v;
        } else {
          if (col < 47)
            Pb[(size_t)nd * 128 + hf * 64 + col] = f2b(v);
          else if (col < 94)
            Rf[(size_t)nd * 128 + hf * 64 + (col - 47)] = v;
        }
      }
    }
  }
}

// ------------------------------ aggregation --------------------------------
// 1 wave per NODE, both branches. lane: half=lane>>5 -> branch, 4 cols/lane.
// One 512B gather request per edge (uint2/lane), unrolled x8 for MLP.
template <bool WF32>
__global__ __launch_bounds__(256) void agg_dual128(
    const ushort* __restrict__ P2, const float* __restrict__ R2,
    const float* __restrict__ bias, const int* __restrict__ off,
    const int* __restrict__ csr, float* __restrict__ f0,
    float* __restrict__ f1, ushort* __restrict__ bout, int N) {
  int node = (blockIdx.x * blockDim.x + threadIdx.x) >> 6;
  int lane = threadIdx.x & 63;
  if (node >= N) return;
  int half = lane >> 5, lq = lane & 31;
  int b = off[node], e = off[node + 1];
  float a0 = 0.f, a1 = 0.f, a2 = 0.f, a3 = 0.f;
  float c0 = 0.f, c1 = 0.f, c2 = 0.f, c3 = 0.f;
  int j = b;
  for (; j + 8 <= e; j += 8) {
    int s0 = csr[j], s1 = csr[j + 1], s2 = csr[j + 2], s3 = csr[j + 3];
    int s4 = csr[j + 4], s5 = csr[j + 5], s6 = csr[j + 6], s7 = csr[j + 7];
    uint2 u0 = *(const uint2*)(P2 + (size_t)s0 * 256 + 4 * lane);
    uint2 u1 = *(const uint2*)(P2 + (size_t)s1 * 256 + 4 * lane);
    uint2 u2 = *(const uint2*)(P2 + (size_t)s2 * 256 + 4 * lane);
    uint2 u3 = *(const uint2*)(P2 + (size_t)s3 * 256 + 4 * lane);
    uint2 u4 = *(const uint2*)(P2 + (size_t)s4 * 256 + 4 * lane);
    uint2 u5 = *(const uint2*)(P2 + (size_t)s5 * 256 + 4 * lane);
    uint2 u6 = *(const uint2*)(P2 + (size_t)s6 * 256 + 4 * lane);
    uint2 u7 = *(const uint2*)(P2 + (size_t)s7 * 256 + 4 * lane);
    a0 += b2f_lo(u0.x) + b2f_lo(u1.x) + b2f_lo(u2.x) + b2f_lo(u3.x);
    a1 += b2f_hi(u0.x) + b2f_hi(u1.x) + b2f_hi(u2.x) + b2f_hi(u3.x);
    a2 += b2f_lo(u0.y) + b2f_lo(u1.y) + b2f_lo(u2.y) + b2f_lo(u3.y);
    a3 += b2f_hi(u0.y) + b2f_hi(u1.y) + b2f_hi(u2.y) + b2f_hi(u3.y);
    c0 += b2f_lo(u4.x) + b2f_lo(u5.x) + b2f_lo(u6.x) + b2f_lo(u7.x);
    c1 += b2f_hi(u4.x) + b2f_hi(u5.x) + b2f_hi(u6.x) + b2f_hi(u7.x);
    c2 += b2f_lo(u4.y) + b2f_lo(u5.y) + b2f_lo(u6.y) + b2f_lo(u7.y);
    c3 += b2f_hi(u4.y) + b2f_hi(u5.y) + b2f_hi(u6.y) + b2f_hi(u7.y);
  }
  if (j + 4 <= e) {
    int s0 = csr[j], s1 = csr[j + 1], s2 = csr[j + 2], s3 = csr[j + 3];
    uint2 u0 = *(const uint2*)(P2 + (size_t)s0 * 256 + 4 * lane);
    uint2 u1 = *(const uint2*)(P2 + (size_t)s1 * 256 + 4 * lane);
    uint2 u2 = *(const uint2*)(P2 + (size_t)s2 * 256 + 4 * lane);
    uint2 u3 = *(const uint2*)(P2 + (size_t)s3 * 256 + 4 * lane);
    a0 += b2f_lo(u0.x) + b2f_lo(u1.x) + b2f_lo(u2.x) + b2f_lo(u3.x);
    a1 += b2f_hi(u0.x) + b2f_hi(u1.x) + b2f_hi(u2.x) + b2f_hi(u3.x);
    a2 += b2f_lo(u0.y) + b2f_lo(u1.y) + b2f_lo(u2.y) + b2f_lo(u3.y);
    a3 += b2f_hi(u0.y) + b2f_hi(u1.y) + b2f_hi(u2.y) + b2f_hi(u3.y);
    j += 4;
  }
  for (; j < e; ++j) {
    uint2 u0 = *(const uint2*)(P2 + (size_t)csr[j] * 256 + 4 * lane);
    a0 += b2f_lo(u0.x);
    a1 += b2f_hi(u0.x);
    a2 += b2f_lo(u0.y);
    a3 += b2f_hi(u0.y);
  }
  a0 += c0; a1 += c1; a2 += c2; a3 += c3;
  float invd = 1.f / (float)max(e - b, 1);
  float4 rv = *(const float4*)(R2 + (size_t)node * 256 + 4 * lane);
  float4 bb = *(const float4*)(bias + 4 * lq);
  float o0 = fmaxf(a0 * invd + bb.x + rv.x, 0.f);
  float o1 = fmaxf(a1 * invd + bb.y + rv.y, 0.f);
  float o2 = fmaxf(a2 * invd + bb.z + rv.z, 0.f);
  float o3 = fmaxf(a3 * invd + bb.w + rv.w, 0.f);
  size_t arow = (size_t)(half ? N + node : node) * 128 + 4 * lq;
  ushort4 pk;
  pk.x = f2b(o0); pk.y = f2b(o1); pk.z = f2b(o2); pk.w = f2b(o3);
  *(ushort4*)(bout + arow) = pk;
  if (WF32) {
    float* dst = (half ? f1 : f0) + (size_t)node * 128 + 4 * lq;
    *(float4*)dst = make_float4(o0, o1, o2, o3);
  }
}

// layer 2: Pz/Rz [node][2][64]; 1 wave per node, 2 cols/lane; fused softmax.
__global__ __launch_bounds__(256) void agg47_dual(
    const ushort* __restrict__ Pz, const float* __restrict__ Rz,
    const float* __restrict__ bias, const int* __restrict__ off,
    const int* __restrict__ csr, float* __restrict__ z0,
    float* __restrict__ z1, float* __restrict__ y0, float* __restrict__ y1,
    int N) {
  int node = (blockIdx.x * blockDim.x + threadIdx.x) >> 6;
  int lane = threadIdx.x & 63;
  if (node >= N) return;
  int half = lane >> 5, lq = lane & 31;
  int c0 = 2 * lq, c1 = 2 * lq + 1;
  bool v0 = c0 < 47, v1 = c1 < 47;
  int b = off[node], e = off[node + 1];
  float a0 = 0.f, a1 = 0.f, d0 = 0.f, d1 = 0.f;
  int j = b;
  for (; j + 8 <= e; j += 8) {
    int s0 = csr[j], s1 = csr[j + 1], s2 = csr[j + 2], s3 = csr[j + 3];
    int s4 = csr[j + 4], s5 = csr[j + 5], s6 = csr[j + 6], s7 = csr[j + 7];
    uint u0 = *(const uint*)(Pz + (size_t)s0 * 128 + 2 * lane);
    uint u1 = *(const uint*)(Pz + (size_t)s1 * 128 + 2 * lane);
    uint u2 = *(const uint*)(Pz + (size_t)s2 * 128 + 2 * lane);
    uint u3 = *(const uint*)(Pz + (size_t)s3 * 128 + 2 * lane);
    uint u4 = *(const uint*)(Pz + (size_t)s4 * 128 + 2 * lane);
    uint u5 = *(const uint*)(Pz + (size_t)s5 * 128 + 2 * lane);
    uint u6 = *(const uint*)(Pz + (size_t)s6 * 128 + 2 * lane);
    uint u7 = *(const uint*)(Pz + (size_t)s7 * 128 + 2 * lane);
    a0 += b2f_lo(u0) + b2f_lo(u1) + b2f_lo(u2) + b2f_lo(u3);
    a1 += b2f_hi(u0) + b2f_hi(u1) + b2f_hi(u2) + b2f_hi(u3);
    d0 += b2f_lo(u4) + b2f_lo(u5) + b2f_lo(u6) + b2f_lo(u7);
    d1 += b2f_hi(u4) + b2f_hi(u5) + b2f_hi(u6) + b2f_hi(u7);
  }
  if (j + 4 <= e) {
    int s0 = csr[j], s1 = csr[j + 1], s2 = csr[j + 2], s3 = csr[j + 3];
    uint u0 = *(const uint*)(Pz + (size_t)s0 * 128 + 2 * lane);
    uint u1 = *(const uint*)(Pz + (size_t)s1 * 128 + 2 * lane);
    uint u2 = *(const uint*)(Pz + (size_t)s2 * 128 + 2 * lane);
    uint u3 = *(const uint*)(Pz + (size_t)s3 * 128 + 2 * lane);
    a0 += b2f_lo(u0) + b2f_lo(u1) + b2f_lo(u2) + b2f_lo(u3);
    a1 += b2f_hi(u0) + b2f_hi(u1) + b2f_hi(u2) + b2f_hi(u3);
    j += 4;
  }
  for (; j < e; ++j) {
    uint u0 = *(const uint*)(Pz + (size_t)csr[j] * 128 + 2 * lane);
    a0 += b2f_lo(u0);
    a1 += b2f_hi(u0);
  }
  a0 += d0; a1 += d1;
  float invd = 1.f / (float)max(e - b, 1);
  float2 rv = *(const float2*)(Rz + (size_t)node * 128 + 2 * lane);
  float za = v0 ? (a0 * invd + bias[c0] + rv.x) : -INFINITY;
  float zb = v1 ? (a1 * invd + bias[c1] + rv.y) : -INFINITY;
  // half-wave (branch) reduction: xor masks <=16 stay within 32-lane half
  float m = fmaxf(za, zb);
#pragma unroll
  for (int d = 1; d < 32; d <<= 1) m = fmaxf(m, __shfl_xor(m, d, 64));
  float s = (v0 ? __expf(za - m) : 0.f) + (v1 ? __expf(zb - m) : 0.f);
#pragma unroll
  for (int d = 1; d < 32; d <<= 1) s += __shfl_xor(s, d, 64);
  float ls = logf(s) + m;
  float* zo = (half ? z1 : z0) + (size_t)node * 47;
  float* yo = (half ? y1 : y0) + (size_t)node * 47;
  if (v0) { zo[c0] = za; yo[c0] = za - ls; }
  if (v1) { zo[c1] = zb; yo[c1] = zb - ls; }
}

// ---------------------------------------------------------------------------
extern "C" void kernel_launch(void* const* d_in, const int* in_sizes, int n_in,
                              void* d_out, int out_size, void* d_ws,
                              size_t ws_size, hipStream_t stream) {
  const float* x = (const float*)d_in[0];
  const int* ei = (const int*)d_in[1];
  const float* noise = (const float*)d_in[2];
  const float* Wl0 = (const float*)d_in[3];
  const float* bl0 = (const float*)d_in[4];
  const float* Wr0 = (const float*)d_in[5];
  const float* Wl1 = (const float*)d_in[6];
  const float* bl1 = (const float*)d_in[7];
  const float* Wr1 = (const float*)d_in[8];
  const float* Wl2 = (const float*)d_in[9];
  const float* bl2 = (const float*)d_in[10];
  const float* Wr2 = (const float*)d_in[11];

  const int N = in_sizes[0] / 128;
  const int E = in_sizes[1] / 2;
  const int M = 2 * N;

  float* out = (float*)d_out;
  float* h_p = out;
  float* y_p = h_p + (size_t)N * 128;
  float* z_p = y_p + (size_t)N * 47;
  float* h_n = z_p + (size_t)N * 47;
  float* y_n = h_n + (size_t)N * 128;
  float* z_n = y_n + (size_t)N * 47;

  char* w = (char*)d_ws;
  auto alloc = [&](size_t bytes) {
    void* p = (void*)w;
    w += (bytes + 511) & ~(size_t)511;
    return p;
  };
  ushort* XB = (ushort*)alloc((size_t)M * 128 * 2);   // activations bf16 [M][128]
  ushort* Pb = (ushort*)alloc((size_t)M * 128 * 2);   // P2 / Pz interleaved
  float* Rf = (float*)alloc((size_t)M * 128 * 4);     // R2 / Rz interleaved
  ushort* WB0 = (ushort*)alloc(256 * 128 * 2);
  ushort* WB1 = (ushort*)alloc(256 * 128 * 2);
  ushort* WB2 = (ushort*)alloc(94 * 128 * 2);
  int* cnt = (int*)alloc((size_t)N * 4);
  int* off = (int*)alloc((size_t)(N + 1) * 4);
  int* cur = (int*)alloc((size_t)N * 4);
  int* loc = (int*)alloc((size_t)N * 4);
  int* bsum = (int*)alloc((size_t)256 * 4);
  int* csr = (int*)alloc((size_t)E * 4);

  conv_weights<<<(16384 + 255) / 256, 256, 0, stream>>>(
      Wl0, Wr0, Wl1, Wr1, Wl2, Wr2, WB0, WB1, WB2);

  // CSR build
  hipMemsetAsync(cnt, 0, (size_t)N * 4, stream);
  int eb = (E + 255) / 256;
  count_kernel<<<eb, 256, 0, stream>>>(ei + E, cnt, E);
  int sb = (N + 1023) / 1024;
  scan_blocks<<<sb, 256, 0, stream>>>(cnt, loc, bsum, N);
  scan_bsums<<<1, 256, 0, stream>>>(bsum, sb);
  scan_apply<<<(N + 255) / 256, 256, 0, stream>>>(loc, bsum, off, cur, N, E);
  fill_kernel<<<eb, 256, 0, stream>>>(ei, ei + E, cur, csr, E);

  int nwb = (N + 3) / 4;       // 1 wave/node
  int rb = (M + 127) / 128;    // GEMM row blocks

  noisy_convert<<<nwb, 256, 0, stream>>>(x, noise, XB, N);

  // layer 0
  gemm_bf16<4, false><<<dim3(rb, 2), 256, 0, stream>>>(XB, WB0, Pb, Rf, M);
  agg_dual128<false><<<nwb, 256, 0, stream>>>(Pb, Rf, bl0, off, csr, nullptr,
                                              nullptr, XB, N);
  // layer 1 (h outputs + bf16 for next layer)
  gemm_bf16<4, false><<<dim3(rb, 2), 256, 0, stream>>>(XB, WB1, Pb, Rf, M);
  agg_dual128<true><<<nwb, 256, 0, stream>>>(Pb, Rf, bl1, off, csr, h_p, h_n,
                                             XB, N);
  // layer 2 + fused log_softmax
  gemm_bf16<3, true><<<dim3(rb, 1), 256, 0, stream>>>(XB, WB2, Pb, Rf, M);
  agg47_dual<<<nwb, 256, 0, stream>>>(Pb, Rf, bl2, off, csr, z_p, z_n, y_p,
                                      y_n, N);
}